// Round 1
// baseline (237.260 us; speedup 1.0000x reference)
//
#include <hip/hip_runtime.h>
#include <hip/hip_bf16.h>

// Problem shape (fixed by the reference setup_inputs)
constexpr int B = 16, F = 16, H = 256, W = 256;
constexpr int HW = H * W;            // 65536
constexpr int SPATIAL = B * HW;      // 1,048,576 spatial locations (b,h,w)
constexpr int NBLOCKS = 1024;
constexpr int NTHREADS = 256;
constexpr int NVALS = 65;            // s[16], c[16], dtot[16], sall[16], call

__inline__ __device__ float wave_reduce_sum(float v) {
    #pragma unroll
    for (int o = 32; o > 0; o >>= 1) v += __shfl_down(v, o, 64);
    return v;
}

// One pass: each thread owns spatial locations (grid-stride), loops the 16
// features (stride HW, coalesced across lanes), computes m_all inline.
// Per-block 65 partial sums written (deterministically) to d_ws.
__global__ __launch_bounds__(NTHREADS) void heatloss_main(
        const float* __restrict__ inp, const float* __restrict__ tgt,
        const unsigned char* __restrict__ msk, float* __restrict__ partials) {
    float s[F], c[F], dtot[F], sall[F];
    #pragma unroll
    for (int f = 0; f < F; f++) { s[f] = 0.f; c[f] = 0.f; dtot[f] = 0.f; sall[f] = 0.f; }
    float call = 0.f;

    const int stride = gridDim.x * blockDim.x;
    for (int pos = blockIdx.x * blockDim.x + threadIdx.x; pos < SPATIAL; pos += stride) {
        const int b  = pos >> 16;          // pos / HW
        const int hw = pos & (HW - 1);     // pos % HW
        const int base = b * (F * HW) + hw;
        float diff[F];
        float anyf = 0.f;
        #pragma unroll
        for (int f = 0; f < F; f++) {
            const int idx = base + f * HW;
            const float d  = fabsf(inp[idx] - tgt[idx]);
            const float mf = (float)msk[idx];   // 0.0 or 1.0
            diff[f] = d;
            dtot[f] += d;
            s[f]    += mf * d;
            c[f]    += mf;
            anyf    += mf;
        }
        const float af = (anyf > 0.f) ? 1.f : 0.f;   // m_all at this location
        call += af;
        #pragma unroll
        for (int f = 0; f < F; f++) sall[f] += af * diff[f];
    }

    // Block reduction: wave shuffle -> LDS across 4 waves -> write partials
    __shared__ float red[NTHREADS / 64][NVALS];
    const int lane = threadIdx.x & 63;
    const int wave = threadIdx.x >> 6;
    #pragma unroll
    for (int v = 0; v < NVALS; v++) {
        float x = (v < 16) ? s[v]
                : (v < 32) ? c[v - 16]
                : (v < 48) ? dtot[v - 32]
                : (v < 64) ? sall[v - 48]
                : call;
        x = wave_reduce_sum(x);
        if (lane == 0) red[wave][v] = x;
    }
    __syncthreads();
    if (threadIdx.x < NVALS) {
        const int v = threadIdx.x;
        float t = 0.f;
        #pragma unroll
        for (int w2 = 0; w2 < NTHREADS / 64; w2++) t += red[w2][v];
        partials[v * gridDim.x + blockIdx.x] = t;   // layout [65][NBLOCKS]
    }
}

// Single block: sum the per-block partials and emit the scalar loss.
__global__ __launch_bounds__(512) void heatloss_finalize(
        const float* __restrict__ partials, float* __restrict__ out, int nblocks) {
    __shared__ float acc[NVALS][4];
    __shared__ float vals[NVALS];
    const int t = threadIdx.x;
    const int v = t >> 2, j = t & 3;
    if (v < NVALS) {
        const int per = nblocks >> 2;
        const float* p = partials + v * nblocks + j * per;
        float sum = 0.f;
        for (int i = 0; i < per; i++) sum += p[i];
        acc[v][j] = sum;
    }
    __syncthreads();
    if (t < NVALS) vals[t] = acc[t][0] + acc[t][1] + acc[t][2] + acc[t][3];
    __syncthreads();
    if (t == 0) {
        const float Nf = (float)SPATIAL;  // per-feature element count (B*H*W)
        const float call = vals[64];
        float lf = 0.f, lbg = 0.f, lall = 0.f;
        #pragma unroll
        for (int f = 0; f < F; f++) {
            const float sf = vals[f], cf = vals[16 + f];
            const float dt = vals[32 + f], sa = vals[48 + f];
            lf += (cf > 0.f) ? sf / cf : 0.f;
            const float sbg = dt - sf, cbg = Nf - cf;
            lbg += (cbg > 0.f) ? sbg / cbg : 0.f;
            lall += (call > 0.f) ? sa / call : 0.f;
        }
        out[0] = (lf / 16.f + lbg / 16.f + lall / 16.f) / 3.f;
    }
}

extern "C" void kernel_launch(void* const* d_in, const int* in_sizes, int n_in,
                              void* d_out, int out_size, void* d_ws, size_t ws_size,
                              hipStream_t stream) {
    const float*         inp = (const float*)d_in[0];
    const float*         tgt = (const float*)d_in[1];
    const unsigned char* msk = (const unsigned char*)d_in[2];   // jnp.bool_ -> 1 byte
    float* out      = (float*)d_out;
    float* partials = (float*)d_ws;   // NVALS * NBLOCKS floats = 266 KB

    heatloss_main<<<NBLOCKS, NTHREADS, 0, stream>>>(inp, tgt, msk, partials);
    heatloss_finalize<<<1, 512, 0, stream>>>(partials, out, NBLOCKS);
}

// Round 2
// 203.641 us; speedup vs baseline: 1.1651x; 1.1651x over previous
//
#include <hip/hip_runtime.h>
#include <hip/hip_bf16.h>

// Problem shape (fixed by the reference setup_inputs)
constexpr int B = 16, F = 16, H = 256, W = 256;
constexpr int HW = H * W;               // 65536
constexpr int SPATIAL = B * HW;         // 1,048,576 spatial locations
constexpr int NBLOCKS = 1024;
constexpr int NTHREADS = 256;
constexpr int NVALS = 65;               // s[16], c[16], dtot[16], sall[16], call
constexpr int PLANE4 = HW / 4;          // 16384 float4 per (b,f) plane
constexpr int BSTRIDE4 = F * PLANE4;    // 262144 float4 per batch index

__inline__ __device__ float wave_reduce_sum(float v) {
    #pragma unroll
    for (int o = 32; o > 0; o >>= 1) v += __shfl_down(v, o, 64);
    return v;
}

// One pass, 4 positions/thread via float4 + uint(4-byte) mask loads.
// Exactly one position-group per thread: 1024 blk * 256 thr * 4 = SPATIAL.
__global__ __launch_bounds__(NTHREADS) void heatloss_main(
        const float4* __restrict__ inp, const float4* __restrict__ tgt,
        const unsigned int* __restrict__ msk, float* __restrict__ partials) {
    const int g   = blockIdx.x * NTHREADS + threadIdx.x;  // group id [0, 262144)
    const int b   = g >> 14;                              // g / PLANE4
    const int hw4 = g & (PLANE4 - 1);
    const int base = b * BSTRIDE4 + hw4;

    // Load all 16 mask words first (needed for m_all before accumulation).
    unsigned int m[F];
    #pragma unroll
    for (int f = 0; f < F; f++) m[f] = msk[base + f * PLANE4];

    unsigned int anyu = 0;
    #pragma unroll
    for (int f = 0; f < F; f++) anyu |= m[f];
    const float af0 = (anyu & 0x000000FFu) ? 1.f : 0.f;
    const float af1 = (anyu & 0x0000FF00u) ? 1.f : 0.f;
    const float af2 = (anyu & 0x00FF0000u) ? 1.f : 0.f;
    const float af3 = (anyu & 0xFF000000u) ? 1.f : 0.f;
    const float call = (af0 + af1) + (af2 + af3);

    float s[F], c[F], dtot[F], sall[F];
    #pragma unroll
    for (int f = 0; f < F; f++) {
        const float4 a = inp[base + f * PLANE4];
        const float4 t = tgt[base + f * PLANE4];
        const float d0 = fabsf(a.x - t.x);
        const float d1 = fabsf(a.y - t.y);
        const float d2 = fabsf(a.z - t.z);
        const float d3 = fabsf(a.w - t.w);
        const unsigned int mm = m[f];
        const float m0 = (float)( mm        & 0xFFu);   // v_cvt_f32_ubyte0
        const float m1 = (float)((mm >> 8)  & 0xFFu);
        const float m2 = (float)((mm >> 16) & 0xFFu);
        const float m3 = (float)( mm >> 24);
        dtot[f] = (d0 + d1) + (d2 + d3);
        s[f]    = m0 * d0 + m1 * d1 + m2 * d2 + m3 * d3;
        c[f]    = (m0 + m1) + (m2 + m3);
        sall[f] = af0 * d0 + af1 * d1 + af2 * d2 + af3 * d3;
    }

    // Block reduction: wave shuffle -> LDS across 4 waves -> write partials
    __shared__ float red[NTHREADS / 64][NVALS];
    const int lane = threadIdx.x & 63;
    const int wave = threadIdx.x >> 6;
    #pragma unroll
    for (int v = 0; v < NVALS; v++) {
        float x = (v < 16) ? s[v]
                : (v < 32) ? c[v - 16]
                : (v < 48) ? dtot[v - 32]
                : (v < 64) ? sall[v - 48]
                : call;
        x = wave_reduce_sum(x);
        if (lane == 0) red[wave][v] = x;
    }
    __syncthreads();
    if (threadIdx.x < NVALS) {
        const int v = threadIdx.x;
        float t = 0.f;
        #pragma unroll
        for (int w2 = 0; w2 < NTHREADS / 64; w2++) t += red[w2][v];
        partials[v * NBLOCKS + blockIdx.x] = t;   // layout [65][NBLOCKS]
    }
}

// 8 waves; each wave sums one value's 1024 partials with coalesced loads.
__global__ __launch_bounds__(512) void heatloss_finalize(
        const float* __restrict__ partials, float* __restrict__ out) {
    __shared__ float vals[NVALS];
    const int wave = threadIdx.x >> 6;   // 0..7
    const int lane = threadIdx.x & 63;
    for (int v = wave; v < NVALS; v += 8) {
        const float* p = partials + v * NBLOCKS;
        float x = 0.f;
        #pragma unroll
        for (int i = 0; i < NBLOCKS / 64; i++) x += p[i * 64 + lane];
        x = wave_reduce_sum(x);
        if (lane == 0) vals[v] = x;
    }
    __syncthreads();
    if (threadIdx.x == 0) {
        const float Nf = (float)SPATIAL;  // per-feature element count (B*H*W)
        const float call = vals[64];
        float lf = 0.f, lbg = 0.f, lall = 0.f;
        #pragma unroll
        for (int f = 0; f < F; f++) {
            const float sf = vals[f], cf = vals[16 + f];
            const float dt = vals[32 + f], sa = vals[48 + f];
            lf += (cf > 0.f) ? sf / cf : 0.f;
            const float sbg = dt - sf, cbg = Nf - cf;
            lbg += (cbg > 0.f) ? sbg / cbg : 0.f;
            lall += (call > 0.f) ? sa / call : 0.f;
        }
        out[0] = (lf / 16.f + lbg / 16.f + lall / 16.f) / 3.f;
    }
}

extern "C" void kernel_launch(void* const* d_in, const int* in_sizes, int n_in,
                              void* d_out, int out_size, void* d_ws, size_t ws_size,
                              hipStream_t stream) {
    const float4*       inp = (const float4*)d_in[0];
    const float4*       tgt = (const float4*)d_in[1];
    const unsigned int* msk = (const unsigned int*)d_in[2];   // jnp.bool_ -> 1 byte each
    float* out      = (float*)d_out;
    float* partials = (float*)d_ws;   // NVALS * NBLOCKS floats = 266 KB

    heatloss_main<<<NBLOCKS, NTHREADS, 0, stream>>>(inp, tgt, msk, partials);
    heatloss_finalize<<<1, 512, 0, stream>>>(partials, out);
}